// Round 4
// baseline (389.247 us; speedup 1.0000x reference)
//
#include <hip/hip_runtime.h>
#include <hip/hip_bf16.h>
#include <stdint.h>

#define E_ 768
#define H_ 768
#define C_ 9
#define M_TOTAL 32768
#define BM_ 128          // tokens per block

typedef __attribute__((ext_vector_type(8))) __bf16 bf16x8;
typedef __attribute__((ext_vector_type(4))) float f32x4;
typedef __attribute__((ext_vector_type(4))) int i32x4;

static_assert(sizeof(bf16x8) == 16, "bf16x8 must be 16B");

__device__ __forceinline__ unsigned short f2bf(float f) {
    __hip_bfloat16 h = __float2bfloat16(f);
    return __builtin_bit_cast(unsigned short, h);
}

// ---------------------------------------------------------------------------
// Prep: W1 (fp32 [E][H]) -> bf16 MFMA-B fragment cells, input-coalesced:
//   block = row k, thread = col n; out W1f[((ntile*24+t)*64+lane)*8+j]
//     ntile=n>>4, t=k>>5, lane=(n&15)+16*((k>>3)&3), j=k&7
// Block 768 handles W2 -> W2f (B-frag cells padded to 16 cols) + loss zero.
// ---------------------------------------------------------------------------
__global__ void prep_kernel(const float* __restrict__ W1, const float* __restrict__ W2,
                            unsigned short* __restrict__ W1f, unsigned short* __restrict__ W2f,
                            float* __restrict__ loss_out)
{
    int b = blockIdx.x;
    int n = threadIdx.x;
    if (b < 768) {
        int k = b;
        float v = W1[k * H_ + n];
        int ntile = n >> 4;
        int t = k >> 5;
        int lane = (n & 15) + 16 * ((k >> 3) & 3);
        int j = k & 7;
        W1f[((ntile * 24 + t) * 64 + lane) * 8 + j] = f2bf(v);
    } else {
        // W2f: 12288 slots = 16 iters x 768 threads
        for (int it = 0; it < 16; ++it) {
            int tid = it * 768 + n;
            int j    = tid & 7;
            int lane = (tid >> 3) & 63;
            int t    = tid >> 9;
            int cls  = lane & 15;
            int k = t * 32 + (lane >> 4) * 8 + j;
            W2f[tid] = (cls < C_) ? f2bf(W2[k * C_ + cls]) : (unsigned short)0;
        }
        if (n == 0) *loss_out = 0.0f;
    }
}

// ---------------------------------------------------------------------------
// Fused head kernel, round 4. Block = 128 tokens x full H=768, 8 waves,
// 256 blocks (1/CU). Wave owns 8 mt x 6 nt -> acc[8][6] = 192 f32 (AGPRs);
// __launch_bounds__(512,2) -> 256-reg budget, 2 waves/SIMD. ONE K-pass:
//   A staged fp32->bf16 frag cells in BK=128 double-buffered LDS (2x32 KB),
//   staging split into two 4-float4 halves to cap transient VGPR liveness;
//   B fragments wave-private from W1f (L2, 48 KB/CU/k-step = 857 cyc vs
//   MFMA 1862 cyc/SIMD -> MFMA-bound). Barrier once per 4 k-steps.
// Epilogue: 4 phases of 192 cols (Hsh 48 KB): waves 2c,2c+1 tanh->Hsh,
// all 8 waves logit-MFMA (wave w = row-tile w), softmax + probs + loss.
// ---------------------------------------------------------------------------
__launch_bounds__(512, 2)
__global__ void fused_head_kernel(const float* __restrict__ hidden,
                                  const unsigned short* __restrict__ W1f,
                                  const float* __restrict__ b1,
                                  const unsigned short* __restrict__ W2f,
                                  const float* __restrict__ b2,
                                  const int* __restrict__ labels,
                                  const int* __restrict__ epoch_p,
                                  float* __restrict__ probs,
                                  float* __restrict__ loss)
{
    __shared__ unsigned short Ast[2][16384];   // 2 x 32 KB: A frag cells, BK=128 piece
    __shared__ unsigned short Hsh[24576];      // 48 KB: h frag cells, one 192-col phase

    const int tid  = threadIdx.x;
    const int w    = tid >> 6;     // wave 0..7
    const int lane = tid & 63;
    const int tok0 = blockIdx.x * BM_;
    const int c16  = lane & 15;
    const int q    = lane >> 4;

    // ---- staging invariants: thread (w,lane) stages units u=0..7 (mt=u) ----
    // element: token = tok0 + u*16 + c16, k = s*128 + (w>>1)*32 + q*8 + (w&1)*4 + 0..3
    // LDS elem offset = ((w>>1)*8 + u)*512 + lane*8 + (w&1)*4
    const int sg_jb = (w & 1) * 4;
    const float* gbase = hidden + (size_t)(tok0 + c16) * E_ + (w >> 1) * 32 + q * 8 + sg_jb;
    const int lbase = (w >> 1) * 4096 + lane * 8 + sg_jb;

    // ---- B-fragment base: wave-private n-tiles w*6+nt ----
    const unsigned short* Wp = W1f + (size_t)(w * 6 * 24) * 512 + lane * 8;

    // ---- prologue: stage piece 0 into buf 0 ----
    {
        float4 v[8];
        #pragma unroll
        for (int u = 0; u < 8; ++u) v[u] = *(const float4*)(gbase + u * 16 * E_);
        #pragma unroll
        for (int u = 0; u < 8; ++u) {
            ushort4 p = { f2bf(v[u].x), f2bf(v[u].y), f2bf(v[u].z), f2bf(v[u].w) };
            *(ushort4*)(&Ast[0][lbase + u * 512]) = p;
        }
    }
    __syncthreads();

    const f32x4 zero4 = {0.0f, 0.0f, 0.0f, 0.0f};
    f32x4 acc[8][6];
    #pragma unroll
    for (int mt = 0; mt < 8; ++mt)
        #pragma unroll
        for (int nt = 0; nt < 6; ++nt) acc[mt][nt] = zero4;

#define KSTEP(Ab, t, s)                                                              \
    {                                                                                \
        const int tg = (s) * 4 + (t);                                                \
        bf16x8 bfr[6];                                                               \
        _Pragma("unroll")                                                            \
        for (int nt = 0; nt < 6; ++nt)                                               \
            bfr[nt] = __builtin_bit_cast(bf16x8,                                     \
                *(const i32x4*)(Wp + ((size_t)nt * 24 + tg) * 512));                 \
        _Pragma("unroll")                                                            \
        for (int mt = 0; mt < 8; ++mt) {                                             \
            bf16x8 af = __builtin_bit_cast(bf16x8,                                   \
                *(const i32x4*)(&(Ab)[((t) * 8 + mt) * 512 + lane * 8]));            \
            _Pragma("unroll")                                                        \
            for (int nt = 0; nt < 6; ++nt)                                           \
                acc[mt][nt] = __builtin_amdgcn_mfma_f32_16x16x32_bf16(               \
                    af, bfr[nt], acc[mt][nt], 0, 0, 0);                              \
        }                                                                            \
    }

    // ---- K loop: 6 stages x BK=128 (4 k-steps), double-buffered ----
    for (int s = 0; s < 6; ++s) {
        const unsigned short* Ab = Ast[s & 1];
        unsigned short* An = Ast[(s + 1) & 1];
        const bool pf = (s < 5);
        const float* gs = gbase + (s + 1) * 128;
        float4 v[4];
        if (pf) {
            #pragma unroll
            for (int u = 0; u < 4; ++u) v[u] = *(const float4*)(gs + u * 16 * E_);
        }
        KSTEP(Ab, 0, s)
        KSTEP(Ab, 1, s)
        if (pf) {
            #pragma unroll
            for (int u = 0; u < 4; ++u) {
                ushort4 p = { f2bf(v[u].x), f2bf(v[u].y), f2bf(v[u].z), f2bf(v[u].w) };
                *(ushort4*)(&An[lbase + u * 512]) = p;
            }
            #pragma unroll
            for (int u = 0; u < 4; ++u) v[u] = *(const float4*)(gs + (u + 4) * 16 * E_);
        }
        KSTEP(Ab, 2, s)
        KSTEP(Ab, 3, s)
        if (pf) {
            #pragma unroll
            for (int u = 0; u < 4; ++u) {
                ushort4 p = { f2bf(v[u].x), f2bf(v[u].y), f2bf(v[u].z), f2bf(v[u].w) };
                *(ushort4*)(&An[lbase + (u + 4) * 512]) = p;
            }
        }
        __syncthreads();
    }
#undef KSTEP

    // ---- epilogue: 4 phases of 192 cols; waves 2c,2c+1 own phase c ----
    f32x4 logit = zero4;   // wave w: logits for rows w*16..w*16+15
    const int myc = w >> 1;
    for (int c = 0; c < 4; ++c) {
        if (myc == c) {
            #pragma unroll
            for (int i = 0; i < 6; ++i) {
                int kloc = (w & 1) * 96 + i * 16 + c16;    // phase-local h-col 0..191
                float b1v = b1[w * 96 + i * 16 + c16];     // global col
                int t2 = kloc >> 5;
                int q2 = (kloc >> 3) & 3;
                int j  = kloc & 7;
                #pragma unroll
                for (int mt = 0; mt < 8; ++mt) {
                    #pragma unroll
                    for (int r = 0; r < 4; ++r) {
                        float z = acc[mt][i][r] + b1v;
                        // tanh(z) = 1 - 2/(exp(2z)+1), exp via native exp2
                        float e = exp2f(z * 2.8853900817779268f);
                        float th = 1.0f - 2.0f * __builtin_amdgcn_rcpf(e + 1.0f);
                        int lanep = (q * 4 + r) + 16 * q2;  // frag lane for row mt*16+q*4+r
                        Hsh[((t2 * 8 + mt) * 64 + lanep) * 8 + j] = f2bf(th);
                    }
                }
            }
        }
        __syncthreads();   // h phase visible
        #pragma unroll
        for (int t2 = 0; t2 < 6; ++t2) {
            bf16x8 ha = __builtin_bit_cast(bf16x8, *(const i32x4*)(&Hsh[((t2 * 8 + w) * 64 + lane) * 8]));
            bf16x8 wb = __builtin_bit_cast(bf16x8, *(const i32x4*)(W2f + ((size_t)(c * 6 + t2) * 64 + lane) * 8));
            logit = __builtin_amdgcn_mfma_f32_16x16x32_bf16(ha, wb, logit, 0, 0, 0);
        }
        __syncthreads();   // logit reads done before next phase rewrites Hsh
    }

    // ---- softmax over 9 classes (16-lane groups), probs store, loss ----
    {
        const bool valid = (c16 < C_);
        const float b2v = valid ? b2[c16] : 0.0f;
        const int ep = epoch_p[0];
        float lsum = 0.0f;
        #pragma unroll
        for (int r = 0; r < 4; ++r) {
            float l = valid ? (logit[r] + b2v) : -3.0e38f;
            float m = l;
            #pragma unroll
            for (int d = 1; d < 16; d <<= 1)
                m = fmaxf(m, __shfl_xor(m, d, 64));
            float e = valid ? exp2f((l - m) * 1.44269504f) : 0.0f;
            float s = e;
            #pragma unroll
            for (int d = 1; d < 16; d <<= 1)
                s += __shfl_xor(s, d, 64);
            float p = e / s;
            int row = tok0 + w * 16 + q * 4 + r;
            if (valid) probs[(size_t)row * C_ + c16] = p;
            int lab = labels[row];
            if (valid && lab == c16) {
                float wgt = (ep <= 2) ? 1.0f : ((p > 0.7f) ? 1.0f : 0.0f);
                if (wgt > 0.0f)
                    lsum += (1.0f - exp2f(0.7f * log2f(p))) * (1.0f / 0.7f);
            }
        }
        #pragma unroll
        for (int d = 1; d < 64; d <<= 1)
            lsum += __shfl_xor(lsum, d, 64);
        if (lane == 0) atomicAdd(loss, lsum);
    }
}

// ---------------------------------------------------------------------------
extern "C" void kernel_launch(void* const* d_in, const int* in_sizes, int n_in,
                              void* d_out, int out_size, void* d_ws, size_t ws_size,
                              hipStream_t stream)
{
    const float* hidden = (const float*)d_in[0];
    const float* W1     = (const float*)d_in[1];
    const float* b1     = (const float*)d_in[2];
    const float* W2     = (const float*)d_in[3];
    const float* b2     = (const float*)d_in[4];
    const int*   labels = (const int*)d_in[5];
    const int*   epoch  = (const int*)d_in[6];

    float* probs = (float*)d_out;                       // [32768 x 9]
    float* loss  = probs + (size_t)M_TOTAL * C_;        // scalar at the end

    unsigned short* W1f = (unsigned short*)d_ws;        // 589824 bf16
    unsigned short* W2f = W1f + 48 * 24 * 512;          // 12288 bf16

    prep_kernel<<<769, 768, 0, stream>>>(W1, W2, W1f, W2f, loss);
    fused_head_kernel<<<M_TOTAL / BM_, 512, 0, stream>>>(hidden, W1f, b1, W2f, b2,
                                                         labels, epoch, probs, loss);
}

// Round 5
// 250.157 us; speedup vs baseline: 1.5560x; 1.5560x over previous
//
#include <hip/hip_runtime.h>
#include <hip/hip_bf16.h>
#include <stdint.h>

#define E_ 768
#define H_ 768
#define C_ 9
#define M_TOTAL 32768
#define BM_ 64           // tokens per block (one K-pass, acc fits 256-reg budget)

typedef __attribute__((ext_vector_type(8))) __bf16 bf16x8;
typedef __attribute__((ext_vector_type(4))) float f32x4;
typedef __attribute__((ext_vector_type(4))) int i32x4;

static_assert(sizeof(bf16x8) == 16, "bf16x8 must be 16B");

__device__ __forceinline__ unsigned short f2bf(float f) {
    __hip_bfloat16 h = __float2bfloat16(f);
    return __builtin_bit_cast(unsigned short, h);
}

// ---------------------------------------------------------------------------
// Prep: W1 (fp32 [E][H]) -> bf16 MFMA-B fragment cells, input-coalesced:
//   block = row k, thread = col n; out W1f[((ntile*24+t)*64+lane)*8+j]
//     ntile=n>>4, t=k>>5, lane=(n&15)+16*((k>>3)&3), j=k&7
// Block 768 handles W2 -> W2f (B-frag cells padded to 16 cols) + loss zero.
// ---------------------------------------------------------------------------
__global__ void prep_kernel(const float* __restrict__ W1, const float* __restrict__ W2,
                            unsigned short* __restrict__ W1f, unsigned short* __restrict__ W2f,
                            float* __restrict__ loss_out)
{
    int b = blockIdx.x;
    int n = threadIdx.x;
    if (b < 768) {
        int k = b;
        float v = W1[k * H_ + n];
        int ntile = n >> 4;
        int t = k >> 5;
        int lane = (n & 15) + 16 * ((k >> 3) & 3);
        int j = k & 7;
        W1f[((ntile * 24 + t) * 64 + lane) * 8 + j] = f2bf(v);
    } else {
        // W2f: 12288 slots = 16 iters x 768 threads
        for (int it = 0; it < 16; ++it) {
            int tid = it * 768 + n;
            int j    = tid & 7;
            int lane = (tid >> 3) & 63;
            int t    = tid >> 9;
            int cls  = lane & 15;
            int k = t * 32 + (lane >> 4) * 8 + j;
            W2f[tid] = (cls < C_) ? f2bf(W2[k * C_ + cls]) : (unsigned short)0;
        }
        if (n == 0) *loss_out = 0.0f;
    }
}

// ---------------------------------------------------------------------------
// Fused head kernel, round 5. Block = 64 tokens x full H=768, 8 waves,
// grid 512 (1 block/CU, two generations). Wave owns 4 mt x 6 nt (n-tiles
// w*6..w*6+5) -> acc[4][6] = 96 f32. Register budget honest this time:
// 96 acc + ~110 working VGPRs < 256 @ __launch_bounds__(512,2) -> NO SPILL
// (R3/R4 both spilled acc; check = WRITE_SIZE stays ~1.2 MB).
// ONE K-pass: A staged fp32->bf16 frag cells, BK=128 double-buffered LDS
// (2 x 16 KB); B fragments wave-private, register-direct from W1f via L2
// (48 KB/CU/k-step = 857 cyc vs MFMA 811 cyc -> ~L2-B-tied, acceptable).
// Barrier once per 4 k-steps. Epilogue: 4 phases of 192 cols (Hsh 24 KB):
// waves 2c,2c+1 tanh->Hsh, waves 0-3 logit-MFMA, softmax + probs + loss.
// ---------------------------------------------------------------------------
__launch_bounds__(512, 2)
__global__ void fused_head_kernel(const float* __restrict__ hidden,
                                  const unsigned short* __restrict__ W1f,
                                  const float* __restrict__ b1,
                                  const unsigned short* __restrict__ W2f,
                                  const float* __restrict__ b2,
                                  const int* __restrict__ labels,
                                  const int* __restrict__ epoch_p,
                                  float* __restrict__ probs,
                                  float* __restrict__ loss)
{
    __shared__ unsigned short Ast[2][8192];    // 2 x 16 KB: A frag cells, BK=128 piece
    __shared__ unsigned short Hsh[12288];      // 24 KB: h frag cells, one 192-col phase

    const int tid  = threadIdx.x;
    const int w    = tid >> 6;     // wave 0..7
    const int lane = tid & 63;
    const int tok0 = blockIdx.x * BM_;
    const int c16  = lane & 15;
    const int q    = lane >> 4;

    // ---- staging invariants: thread (w,lane) stages units u=0..3 (mt=u) ----
    // element: token = tok0 + u*16 + c16, k = s*128 + (w>>1)*32 + q*8 + (w&1)*4 + 0..3
    // LDS short-addr = ((w>>1)*4 + u)*512 + lane*8 + (w&1)*4
    const int sg_jb = (w & 1) * 4;
    const float* gbase = hidden + (size_t)(tok0 + c16) * E_ + (w >> 1) * 32 + q * 8 + sg_jb;
    const int lbase = (w >> 1) * 2048 + lane * 8 + sg_jb;

    // ---- B-fragment base: wave-private n-tiles w*6+nt ----
    const unsigned short* Wp = W1f + (size_t)(w * 6 * 24) * 512 + lane * 8;

    // ---- prologue: stage piece 0 into buf 0 ----
    {
        float4 v[4];
        #pragma unroll
        for (int u = 0; u < 4; ++u) v[u] = *(const float4*)(gbase + u * 16 * E_);
        #pragma unroll
        for (int u = 0; u < 4; ++u) {
            ushort4 p = { f2bf(v[u].x), f2bf(v[u].y), f2bf(v[u].z), f2bf(v[u].w) };
            *(ushort4*)(&Ast[0][lbase + u * 512]) = p;
        }
    }
    __syncthreads();

    const f32x4 zero4 = {0.0f, 0.0f, 0.0f, 0.0f};
    f32x4 acc[4][6];
    #pragma unroll
    for (int mt = 0; mt < 4; ++mt)
        #pragma unroll
        for (int nt = 0; nt < 6; ++nt) acc[mt][nt] = zero4;

#define KSTEP(Ab, t, s)                                                              \
    {                                                                                \
        const int tg = (s) * 4 + (t);                                                \
        bf16x8 bfr[6];                                                               \
        _Pragma("unroll")                                                            \
        for (int nt = 0; nt < 6; ++nt)                                               \
            bfr[nt] = __builtin_bit_cast(bf16x8,                                     \
                *(const i32x4*)(Wp + ((size_t)nt * 24 + tg) * 512));                 \
        _Pragma("unroll")                                                            \
        for (int mt = 0; mt < 4; ++mt) {                                             \
            bf16x8 af = __builtin_bit_cast(bf16x8,                                   \
                *(const i32x4*)(&(Ab)[((t) * 4 + mt) * 512 + lane * 8]));            \
            _Pragma("unroll")                                                        \
            for (int nt = 0; nt < 6; ++nt)                                           \
                acc[mt][nt] = __builtin_amdgcn_mfma_f32_16x16x32_bf16(               \
                    af, bfr[nt], acc[mt][nt], 0, 0, 0);                              \
        }                                                                            \
    }

    // ---- K loop: 6 stages x BK=128 (4 k-steps), double-buffered ----
    for (int s = 0; s < 6; ++s) {
        const unsigned short* Ab = Ast[s & 1];
        unsigned short* An = Ast[(s + 1) & 1];
        const bool pf = (s < 5);
        const float* gs = gbase + (s + 1) * 128;
        float4 v[4];
        if (pf) {
            #pragma unroll
            for (int u = 0; u < 4; ++u) v[u] = *(const float4*)(gs + u * 16 * E_);
        }
        KSTEP(Ab, 0, s)
        KSTEP(Ab, 1, s)
        KSTEP(Ab, 2, s)
        if (pf) {
            #pragma unroll
            for (int u = 0; u < 4; ++u) {
                ushort4 p = { f2bf(v[u].x), f2bf(v[u].y), f2bf(v[u].z), f2bf(v[u].w) };
                *(ushort4*)(&An[lbase + u * 512]) = p;
            }
        }
        KSTEP(Ab, 3, s)
        __syncthreads();
    }
#undef KSTEP

    // ---- epilogue: 4 phases of 192 cols; waves 2c,2c+1 own phase c ----
    f32x4 logit = zero4;   // waves 0-3: logits for rows w*16..w*16+15
    const int myc = w >> 1;
    for (int c = 0; c < 4; ++c) {
        if (myc == c) {
            #pragma unroll
            for (int i = 0; i < 6; ++i) {
                int kloc = (w & 1) * 96 + i * 16 + c16;    // phase-local h-col 0..191
                float b1v = b1[w * 96 + i * 16 + c16];     // global col = c*192 + kloc
                int t2 = kloc >> 5;
                int q2 = (kloc >> 3) & 3;
                int j  = kloc & 7;
                #pragma unroll
                for (int mt = 0; mt < 4; ++mt) {
                    #pragma unroll
                    for (int r = 0; r < 4; ++r) {
                        float z = acc[mt][i][r] + b1v;
                        // tanh(z) = 1 - 2/(exp(2z)+1), exp via native exp2
                        float e = exp2f(z * 2.8853900817779268f);
                        float th = 1.0f - 2.0f * __builtin_amdgcn_rcpf(e + 1.0f);
                        int lanep = (q * 4 + r) + 16 * q2;  // frag lane for row mt*16+q*4+r
                        Hsh[((t2 * 4 + mt) * 64 + lanep) * 8 + j] = f2bf(th);
                    }
                }
            }
        }
        __syncthreads();   // h phase visible
        if (w < 4) {
            #pragma unroll
            for (int t2 = 0; t2 < 6; ++t2) {
                bf16x8 ha = __builtin_bit_cast(bf16x8, *(const i32x4*)(&Hsh[((t2 * 4 + w) * 64 + lane) * 8]));
                bf16x8 wb = __builtin_bit_cast(bf16x8, *(const i32x4*)(W2f + ((size_t)(c * 6 + t2) * 64 + lane) * 8));
                logit = __builtin_amdgcn_mfma_f32_16x16x32_bf16(ha, wb, logit, 0, 0, 0);
            }
        }
        __syncthreads();   // logit reads done before next phase rewrites Hsh
    }

    // ---- softmax over 9 classes (16-lane groups), probs store, loss ----
    if (w < 4) {
        const bool valid = (c16 < C_);
        const float b2v = valid ? b2[c16] : 0.0f;
        const int ep = epoch_p[0];
        float lsum = 0.0f;
        #pragma unroll
        for (int r = 0; r < 4; ++r) {
            float l = valid ? (logit[r] + b2v) : -3.0e38f;
            float m = l;
            #pragma unroll
            for (int d = 1; d < 16; d <<= 1)
                m = fmaxf(m, __shfl_xor(m, d, 64));
            float e = valid ? exp2f((l - m) * 1.44269504f) : 0.0f;
            float s = e;
            #pragma unroll
            for (int d = 1; d < 16; d <<= 1)
                s += __shfl_xor(s, d, 64);
            float p = e / s;
            int row = tok0 + w * 16 + q * 4 + r;
            if (valid) probs[(size_t)row * C_ + c16] = p;
            int lab = labels[row];
            if (valid && lab == c16) {
                float wgt = (ep <= 2) ? 1.0f : ((p > 0.7f) ? 1.0f : 0.0f);
                if (wgt > 0.0f)
                    lsum += (1.0f - exp2f(0.7f * log2f(p))) * (1.0f / 0.7f);
            }
        }
        #pragma unroll
        for (int d = 1; d < 64; d <<= 1)
            lsum += __shfl_xor(lsum, d, 64);
        if (lane == 0) atomicAdd(loss, lsum);
    }
}

// ---------------------------------------------------------------------------
extern "C" void kernel_launch(void* const* d_in, const int* in_sizes, int n_in,
                              void* d_out, int out_size, void* d_ws, size_t ws_size,
                              hipStream_t stream)
{
    const float* hidden = (const float*)d_in[0];
    const float* W1     = (const float*)d_in[1];
    const float* b1     = (const float*)d_in[2];
    const float* W2     = (const float*)d_in[3];
    const float* b2     = (const float*)d_in[4];
    const int*   labels = (const int*)d_in[5];
    const int*   epoch  = (const int*)d_in[6];

    float* probs = (float*)d_out;                       // [32768 x 9]
    float* loss  = probs + (size_t)M_TOTAL * C_;        // scalar at the end

    unsigned short* W1f = (unsigned short*)d_ws;        // 589824 bf16
    unsigned short* W2f = W1f + 48 * 24 * 512;          // 12288 bf16

    prep_kernel<<<769, 768, 0, stream>>>(W1, W2, W1f, W2f, loss);
    fused_head_kernel<<<M_TOTAL / BM_, 512, 0, stream>>>(hidden, W1f, b1, W2f, b2,
                                                         labels, epoch, probs, loss);
}